// Round 4
// baseline (477.881 us; speedup 1.0000x reference)
//
#include <hip/hip_runtime.h>

// Problem: T=2048, B=16, N=2048, binary fp32 spikes, duration=100.
// out[t,b,n] = 1 if any spike in window [t-duration+1, t], else 0.
//
// R0-R3 post-mortem: every source-level ILP scheme (unroll, batch arrays,
// ping-pong + sched_barrier) was re-fused by the compiler to exactly ONE
// outstanding load per wave (VGPR 24-32 each time; measured BW == Little's
// law at ~375ns across all four geometries). This revision buys
// memory-level parallelism with occupancy instead, which the compiler
// cannot undo:
//   CHUNK=128, VEC=1 -> grid (128,16) = 2048 blocks = 8 blocks/CU
//   __launch_bounds__(256,8) -> 32 waves/CU (100% occupancy)
//   8192 waves x 1 outstanding 256B load ~ 2 MB in flight ~ saturation.
// Halo re-reads (99/128 overhead nominal) hit the 256MB Infinity Cache
// (input fits entirely), so HBM fetch stays ~input-sized.

#define T_TOTAL 2048
#define M_COLS  (16 * 2048)   // B*N, contiguous fastest axis
#define CHUNK   128           // time steps per block (16 t-chunks)

__global__ __launch_bounds__(256, 8) void psp_scan_kernel(
    const float* __restrict__ x,
    const int*  __restrict__ dur_p,
    float* __restrict__ out)
{
    const int col = blockIdx.x * blockDim.x + threadIdx.x;   // 0 .. M_COLS-1
    const int t0  = blockIdx.y * CHUNK;
    const int duration = dur_p[0];                           // uniform scalar

    // sentinel: guarantees (t - last) >= duration for all t >= t0 until a spike
    int last = t0 - duration;

    int tstart = t0 - duration + 1;
    if (tstart < 0) tstart = 0;

    const float* __restrict__ xc = x + col;
    float* __restrict__ oc       = out + col;

    // Halo: recover "time of last spike" entering this chunk (L3-resident).
    #pragma unroll 4
    for (int t = tstart; t < t0; ++t) {
        float v = xc[t * M_COLS];
        if (v != 0.0f) last = t;
    }

    // Main chunk: scan + emit.
    #pragma unroll 4
    for (int t = t0; t < t0 + CHUNK; ++t) {
        float v = xc[t * M_COLS];
        if (v != 0.0f) last = t;
        float o = (t - last < duration) ? 1.0f : 0.0f;
        __builtin_nontemporal_store(o, &oc[t * M_COLS]);
    }
}

extern "C" void kernel_launch(void* const* d_in, const int* in_sizes, int n_in,
                              void* d_out, int out_size, void* d_ws, size_t ws_size,
                              hipStream_t stream) {
    const float* x     = (const float*)d_in[0];
    const int*   dur_p = (const int*)d_in[1];
    float*       out   = (float*)d_out;

    dim3 grid(M_COLS / 256, T_TOTAL / CHUNK);   // (128, 16) = 2048 blocks
    dim3 block(256);
    psp_scan_kernel<<<grid, block, 0, stream>>>(x, dur_p, out);
}

// Round 5
// 468.303 us; speedup vs baseline: 1.0205x; 1.0205x over previous
//
#include <hip/hip_runtime.h>

// Problem: T=2048, B=16, N=2048, binary fp32 spikes, duration=100.
// out[t,b,n] = 1 if any spike in window [t-duration+1, t], else 0.
//
// R0-R4 post-mortem: compiler re-fuses every source-level batching scheme
// to ~1 outstanding load per wave (VGPR 12-32 each round); occupancy alone
// (R4: 74%) left BW pinned at 2.5 TB/s because each iteration still
// exposes full load latency (~860ns/iter measured). This revision forces
// 8 loads in flight per wave with inline asm the compiler cannot re-fuse:
//   * 8x asm volatile global_load_dwordx2 per batch (volatile => issued
//     back-to-back, dest regs all live => real MLP)
//   * one asm s_waitcnt vmcnt(0) with "memory" clobber, then
//     sched_barrier(0) (rule #18: stops VALU consumers hoisting past it)
//   * batch-aligned halo (rounded to multiple of 8) so every batch is
//     uniformly halo (no store) or main (store)
// Geometry: VEC=2, CHUNK=128 -> grid (64,16) = 1024 blocks = 4 blocks/CU,
// 16 waves/CU. In-flight ~ 4096 waves x 4KB ~ 12 MB >> 2.4 MB needed.

#define T_TOTAL 2048
#define M_COLS  (16 * 2048)   // B*N, contiguous fastest axis
#define CHUNK   128           // time steps per block (16 t-chunks)
#define VEC     2             // columns per thread (float2)
#define BATCH   8             // asm loads in flight per wave

typedef float v2f __attribute__((ext_vector_type(2)));

#define GLOAD2(dst, ptr) \
    asm volatile("global_load_dwordx2 %0, %1, off" : "=v"(dst) : "v"(ptr))

__global__ __launch_bounds__(256, 4) void psp_scan_kernel(
    const float* __restrict__ x,
    const int*  __restrict__ dur_p,
    float* __restrict__ out)
{
    const int pair = blockIdx.x * blockDim.x + threadIdx.x;  // 0 .. M_COLS/2-1
    const int col  = pair * VEC;
    const int t0   = blockIdx.y * CHUNK;
    const int duration = dur_p[0];                            // uniform scalar

    // Halo rounded up to whole batches; t0 is a multiple of CHUNK (mult of 8).
    int hal = (duration - 1 + (BATCH - 1)) & ~(BATCH - 1);    // 104 for dur=100
    if (hal > t0) hal = t0;
    const int tstart = t0 - hal;

    // sentinel: guarantees (t - last) >= duration until first spike seen
    int last0 = tstart - duration;
    int last1 = last0;

    const v2f* __restrict__ xc = (const v2f*)(x + col);
    v2f* __restrict__ oc       = (v2f*)(out + col);
    const int stride = M_COLS / VEC;   // row stride in float2 units

    v2f v[BATCH];
    int t = tstart;

    // ---- Halo batches: scan only, no stores ----
    for (; t < t0; t += BATCH) {
        #pragma unroll
        for (int i = 0; i < BATCH; ++i) GLOAD2(v[i], xc + (t + i) * stride);
        asm volatile("s_waitcnt vmcnt(0)" ::: "memory");
        __builtin_amdgcn_sched_barrier(0);
        #pragma unroll
        for (int i = 0; i < BATCH; ++i) {
            const int tt = t + i;
            if (v[i].x != 0.0f) last0 = tt;
            if (v[i].y != 0.0f) last1 = tt;
        }
    }

    // ---- Main batches: scan + emit ----
    for (; t < t0 + CHUNK; t += BATCH) {
        #pragma unroll
        for (int i = 0; i < BATCH; ++i) GLOAD2(v[i], xc + (t + i) * stride);
        asm volatile("s_waitcnt vmcnt(0)" ::: "memory");
        __builtin_amdgcn_sched_barrier(0);
        #pragma unroll
        for (int i = 0; i < BATCH; ++i) {
            const int tt = t + i;
            if (v[i].x != 0.0f) last0 = tt;
            if (v[i].y != 0.0f) last1 = tt;
            v2f o;
            o.x = (tt - last0 < duration) ? 1.0f : 0.0f;
            o.y = (tt - last1 < duration) ? 1.0f : 0.0f;
            __builtin_nontemporal_store(o, &oc[tt * stride]);
        }
    }
}

extern "C" void kernel_launch(void* const* d_in, const int* in_sizes, int n_in,
                              void* d_out, int out_size, void* d_ws, size_t ws_size,
                              hipStream_t stream) {
    const float* x     = (const float*)d_in[0];
    const int*   dur_p = (const int*)d_in[1];
    float*       out   = (float*)d_out;

    dim3 grid(M_COLS / VEC / 256, T_TOTAL / CHUNK);   // (64, 16) = 1024 blocks
    dim3 block(256);
    psp_scan_kernel<<<grid, block, 0, stream>>>(x, dur_p, out);
}